// Round 8
// baseline (147.123 us; speedup 1.0000x reference)
//
#include <hip/hip_runtime.h>
#include <math.h>

#define B_   4
#define L_   32768
#define DI   20
#define NS   10
#define TBLK 128          // timesteps per chunk/block
#define NCB  256          // chunks per batch

// fp32 summary offsets in ws (floats)
#define OFF_AP  0u
#define OFF_RS  204800u
#define OFF_SC  409600u
#define OFF_TOT 430080u
#define OFF_H16 430160u   // fp16 region starts here
// fp16 offsets (halves)
#define HD  0u            // delta [80][32768]
#define HU  2621440u      // u     [80][32768]
#define HB  5242880u      // B     [40][32768]
#define HC  6553600u      // C     [40][32768]

typedef _Float16 h16;
typedef _Float16 half8 __attribute__((ext_vector_type(8)));
typedef _Float16 half4 __attribute__((ext_vector_type(4)));
typedef float f32x4 __attribute__((ext_vector_type(4)));

// ---- DPP helpers: row_shr within 16-lane rows, OOB lanes -> identity ----
template<int CTRL>
__device__ __forceinline__ float dppf(float idv, float src) {
    union U { float f; int i; };
    U o, s, r; o.f = idv; s.f = src;
    r.i = __builtin_amdgcn_update_dpp(o.i, s.i, CTRL, 0xf, 0xf, false);
    return r.f;
}
#define ROW_SHR1 0x111
#define ROW_SHR2 0x112
#define ROW_SHR4 0x114
#define ROW_SHR8 0x118

#define OPSCAN16(Ac, Bc) \
    { float aP = dppf<ROW_SHR1>(1.0f, Ac); float bP = dppf<ROW_SHR1>(0.0f, Bc); \
      Bc = fmaf(Ac, bP, Bc); Ac *= aP; \
      aP = dppf<ROW_SHR2>(1.0f, Ac); bP = dppf<ROW_SHR2>(0.0f, Bc); \
      Bc = fmaf(Ac, bP, Bc); Ac *= aP; \
      aP = dppf<ROW_SHR4>(1.0f, Ac); bP = dppf<ROW_SHR4>(0.0f, Bc); \
      Bc = fmaf(Ac, bP, Bc); Ac *= aP; \
      aP = dppf<ROW_SHR8>(1.0f, Ac); bP = dppf<ROW_SHR8>(0.0f, Bc); \
      Bc = fmaf(Ac, bP, Bc); Ac *= aP; }

#define SUMSCAN16(v) \
    { v += dppf<ROW_SHR1>(0.0f, v); v += dppf<ROW_SHR2>(0.0f, v); \
      v += dppf<ROW_SHR4>(0.0f, v); v += dppf<ROW_SHR8>(0.0f, v); }

// ---- k1 LDS layout (halves), total 7948 h16 = 15896 B ----
// Region A (0..5248), time-multiplexed:
//   P0-P2 : xs[130][22]@0 (2860) | WST w_in(400)+ck(1200)@2864 -> MeffT[20][68]@2864 (1360)
//   P2-P4b: UL[128][36]@0 (4608) | xp5[128][5]@4608 (640)
//   P4c+  : DS[20][136]@0 (2720) | CS[10][136]@2720 (1360)
#define XS_   0
#define WST   2864
#define MT_   2864
#define UL_   0
#define XP5_  4608
#define DS__  0
#define CS_   2720
// Region B: persistent
#define BS_   5440   // B staging [10][136] = 1360
#define WX_   6800   // WxT [25][40] = 1000
#define WDTo  7800   // 100
#define BDTo  7900   // 20
#define BXo   7920   // 25
#define POOLH 7948

// =============== k1: MFMA front-end + chunk-local scan ===============
__global__ __launch_bounds__(320) void k1(
    const float* __restrict__ x, const float* __restrict__ w_in,
    const float* __restrict__ b_in, const float* __restrict__ conv_k,
    const float* __restrict__ conv_b, const float* __restrict__ w_x,
    const float* __restrict__ b_x, const float* __restrict__ w_dt,
    const float* __restrict__ b_dt, const float* __restrict__ A_log,
    h16* __restrict__ dh, h16* __restrict__ uh,
    h16* __restrict__ Bh, h16* __restrict__ Ch,
    float* __restrict__ ap_ws, float* __restrict__ rs_ws, float* __restrict__ sc_ws)
{
    __shared__ __align__(16) h16 P[POOLH];
    __shared__ float beff_s[20];

    const int tid = threadIdx.x;
    const int c   = blockIdx.x;
    const int b   = blockIdx.y;
    const int l0  = c * TBLK;

    // ---------- P0: stage weights + x (fp16) ----------
    for (int i = tid; i < 400;  i += 320) P[WST + i]       = (h16)w_in[(i/20)*40 + (i%20)];
    for (int i = tid; i < 1200; i += 320) P[WST + 400 + i] = (h16)conv_k[i];
    // WxT[j][k=d]: w_x[d][j], rows j 0..24
    for (int i = tid; i < 1000; i += 320) {
        int j = i / 40, k = i - j*40;
        P[WX_ + i] = (k < 20) ? (h16)w_x[k*25 + j] : (h16)0.0f;
    }
    for (int i = tid; i < 100; i += 320) P[WDTo + i] = (h16)w_dt[i];
    if (tid < 20) P[BDTo + tid] = (h16)b_dt[tid];
    if (tid < 25) P[BXo  + tid] = (h16)b_x[tid];
    for (int idx = tid; idx < 130*20; idx += 320) {
        int p = idx / 20, i = idx - p*20;
        int l = l0 - 2 + p;
        P[XS_ + p*22 + i] = (l >= 0) ? (h16)x[((size_t)b*L_ + l)*DI + i] : (h16)0.0f;
    }
    __syncthreads();

    // ---------- P1: Meff = w_in @ conv_k (per tap), beff ----------
    float me[4]; int mei[4];
    #pragma unroll
    for (int r = 0; r < 4; r++) {
        int e = tid + r*320;
        float acc = 0.0f;
        if (e < 1200) {
            int cc = e / 20, o = e - cc*20;     // cc=(w,i) 0..59, o 0..19
            int w = cc / 20, i = cc - w*20;
            #pragma unroll
            for (int op = 0; op < 20; op++)
                acc = fmaf((float)P[WST + i*20 + op],
                           (float)P[WST + 400 + (w*20 + op)*20 + o], acc);
        }
        me[r] = acc; mei[r] = e;
    }
    float be = 0.0f;
    if (tid < 20) {
        be = conv_b[tid];
        #pragma unroll
        for (int w = 0; w < 3; w++)
            #pragma unroll
            for (int op = 0; op < 20; op++)
                be = fmaf(b_in[op], (float)P[WST + 400 + (w*20 + op)*20 + tid], be);
    }
    __syncthreads();
    // MeffT[o(row 0..19)][cc(col 0..59)], stride 68; cols 60..67 garbage (A-side k<60 zeros)
    #pragma unroll
    for (int r = 0; r < 4; r++) {
        int e = mei[r];
        if (e < 1200) {
            int cc = e / 20, o = e - cc*20;
            P[MT_ + o*68 + cc] = (h16)me[r];
        }
    }
    if (tid < 20) beff_s[tid] = be;
    __syncthreads();

    // ---------- P2: u_pre = Xwin @ Meff (MFMA), +beff, silu ----------
    const int wv  = tid >> 6;
    const int ln  = tid & 63;
    const int m16 = ln & 15;
    const int q   = ln >> 4;
    float uval[4][4];
    if (wv < 4) {
        #pragma unroll
        for (int jj = 0; jj < 4; jj++) {
            int job = wv*4 + jj, mt = job >> 1, nt = job & 1;
            int t_row = mt*16 + m16;
            int dcol  = nt*16 + m16;
            int dmin  = dcol < 20 ? dcol : 19;
            f32x4 acc = {0.0f, 0.0f, 0.0f, 0.0f};
            #pragma unroll
            for (int kh = 0; kh < 2; kh++) {
                half8 af;
                #pragma unroll
                for (int j = 0; j < 8; j++) {
                    int k = kh*32 + (q<<3) + j;
                    int w = (k >= 20) + (k >= 40);
                    int i = k - 20*w;
                    af[j] = (k < 60) ? P[XS_ + (t_row + w)*22 + i] : (h16)0.0f;
                }
                half8 bf;
                *(half4*)&bf    = *(const half4*)&P[MT_ + dmin*68 + kh*32 + (q<<3)];
                *((half4*)&bf+1)= *(const half4*)&P[MT_ + dmin*68 + kh*32 + (q<<3) + 4];
                acc = __builtin_amdgcn_mfma_f32_16x16x32_f16(af, bf, acc, 0, 0, 0);
            }
            float bf2 = beff_s[dmin];
            #pragma unroll
            for (int r = 0; r < 4; r++) {
                float a = acc[r] + bf2;
                uval[jj][r] = a / (1.0f + __expf(-a));
            }
        }
    }
    __syncthreads();   // xs/MeffT dead -> UL may overwrite
    if (wv < 4) {
        #pragma unroll
        for (int jj = 0; jj < 4; jj++) {
            int job = wv*4 + jj, mt = job >> 1, nt = job & 1;
            int dcol = nt*16 + m16;
            if (dcol < 20) {
                #pragma unroll
                for (int r = 0; r < 4; r++)
                    P[UL_ + (mt*16 + q*4 + r)*36 + dcol] = (h16)uval[jj][r];
            }
        }
    }
    for (int i = tid; i < 128*12; i += 320) {   // zero UL cols 20..31 (A k-pad)
        int t = i / 12, z = i - t*12;
        P[UL_ + t*36 + 20 + z] = (h16)0.0f;
    }
    __syncthreads();

    // ---------- P3: xp = u @ w_x (MFMA), +b_x ----------
    float xv[4][4];
    if (wv < 4) {
        #pragma unroll
        for (int jj = 0; jj < 4; jj++) {
            int job = wv*4 + jj, mt = job >> 1, nt = job & 1;
            int t_row = mt*16 + m16;
            int j     = nt*16 + m16;
            int jmin  = j < 25 ? j : 24;
            f32x4 acc = {0.0f, 0.0f, 0.0f, 0.0f};
            half8 af;
            *(half4*)&af     = *(const half4*)&P[UL_ + t_row*36 + (q<<3)];
            *((half4*)&af+1) = *(const half4*)&P[UL_ + t_row*36 + (q<<3) + 4];
            half8 bf = *(const half8*)&P[WX_ + jmin*40 + (q<<3)];
            acc = __builtin_amdgcn_mfma_f32_16x16x32_f16(af, bf, acc, 0, 0, 0);
            float bx = (j < 25) ? (float)P[BXo + j] : 0.0f;
            #pragma unroll
            for (int r = 0; r < 4; r++) xv[jj][r] = acc[r] + bx;
        }
        // P4a: stash xp5 + BS (no alias with UL reads)
        #pragma unroll
        for (int jj = 0; jj < 4; jj++) {
            int job = wv*4 + jj, nt = job & 1, mt = job >> 1;
            int j = nt*16 + m16;
            #pragma unroll
            for (int r = 0; r < 4; r++) {
                int t_out = mt*16 + q*4 + r;
                if (j < 5)            P[XP5_ + t_out*5 + j]        = (h16)xv[jj][r];
                else if (j < 15)      P[BS_ + (j - 5)*136 + t_out] = (h16)xv[jj][r];
            }
        }
    }
    __syncthreads();

    // ---------- P4b: scan u8 loads (UL); t-threads: uh/Bh coalesced + softmax ----
    const int d  = tid >> 4;
    const int s  = tid & 15;
    const int bd = b*DI + d;

    float u8[8];
    #pragma unroll
    for (int j = 0; j < 8; j++) u8[j] = (float)P[UL_ + (8*s + j)*36 + d];

    float dl[20];
    if (tid < 128) {
        const int t = tid;
        #pragma unroll
        for (int d2 = 0; d2 < 20; d2++)
            uh[(size_t)(b*DI + d2)*L_ + l0 + t] = P[UL_ + t*36 + d2];
        #pragma unroll
        for (int n = 0; n < NS; n++)
            Bh[(size_t)(b*NS + n)*L_ + l0 + t] = P[BS_ + n*136 + t];
        float xq[5];
        #pragma unroll
        for (int r = 0; r < 5; r++) xq[r] = (float)P[XP5_ + t*5 + r];
        #pragma unroll
        for (int d2 = 0; d2 < 20; d2++) dl[d2] = (float)P[BDTo + d2];
        #pragma unroll
        for (int r = 0; r < 5; r++) {
            float dv = xq[r];
            #pragma unroll
            for (int d2 = 0; d2 < 20; d2++)
                dl[d2] = fmaf(dv, (float)P[WDTo + r*20 + d2], dl[d2]);
        }
        float mx = dl[0];
        #pragma unroll
        for (int d2 = 1; d2 < 20; d2++) mx = fmaxf(mx, dl[d2]);
        float sm = 0.0f;
        #pragma unroll
        for (int d2 = 0; d2 < 20; d2++) { dl[d2] = __expf(dl[d2] - mx); sm += dl[d2]; }
        float inv = 1.0f / sm;
        #pragma unroll
        for (int d2 = 0; d2 < 20; d2++) dl[d2] *= inv;
    }
    __syncthreads();   // UL/xp5 dead

    // ---------- P4c: DS + dh writes; CS from xv regs ----------
    if (tid < 128) {
        const int t = tid;
        #pragma unroll
        for (int d2 = 0; d2 < 20; d2++) {
            h16 dlh = (h16)dl[d2];
            P[DS__ + d2*136 + t] = dlh;
            dh[(size_t)(b*DI + d2)*L_ + l0 + t] = dlh;
        }
    }
    if (wv < 4) {
        #pragma unroll
        for (int jj = 0; jj < 4; jj++) {
            int job = wv*4 + jj, nt = job & 1, mt = job >> 1;
            int j = nt*16 + m16;
            if (j >= 15 && j < 25) {
                #pragma unroll
                for (int r = 0; r < 4; r++)
                    P[CS_ + (j - 15)*136 + (mt*16 + q*4 + r)] = (h16)xv[jj][r];
            }
        }
    }
    __syncthreads();

    // ---------- P4d: Ch coalesced; scan d8 ----------
    if (tid < 128) {
        const int t = tid;
        #pragma unroll
        for (int n = 0; n < NS; n++)
            Ch[(size_t)(b*NS + n)*L_ + l0 + t] = P[CS_ + n*136 + t];
    }
    float d8[8], du8[8];
    { half8 hv = *(const half8*)&P[DS__ + d*136 + 8*s];
      #pragma unroll
      for (int j = 0; j < 8; j++) d8[j] = (float)hv[j]; }
    #pragma unroll
    for (int j = 0; j < 8; j++) du8[j] = d8[j]*u8[j];

    // ---------- P5: chunk-local scan ----------
    float ssum = 0.0f;
    #pragma unroll
    for (int j = 0; j < 8; j++) ssum += d8[j];
    SUMSCAN16(ssum);
    if (s == 15) sc_ws[(size_t)bd*NCB + c] = ssum;

    float A_dn[NS];
    #pragma unroll
    for (int n = 0; n < NS; n++) A_dn[n] = -__expf(A_log[d*NS + n]);

    #pragma unroll 1
    for (int n = 0; n < NS; n++) {
        half8 bv = *(const half8*)&P[BS_ + n*136 + 8*s];
        float Ac = 1.0f, Bc = 0.0f;
        #pragma unroll
        for (int j = 0; j < 8; j++) {
            float a = __expf(A_dn[n]*d8[j]);
            Bc = fmaf(a, Bc, du8[j]*(float)bv[j]);
            Ac *= a;
        }
        OPSCAN16(Ac, Bc);
        if (s == 15) {
            size_t o = ((size_t)bd*NS + n)*NCB + c;
            ap_ws[o] = Ac;
            rs_ws[o] = Bc;
        }
    }
}

// =============== kC2: inter-chunk scan (one wave per (b,d)) ===============
__global__ __launch_bounds__(64) void kC2(
    const float* __restrict__ ap_ws, float* __restrict__ rs_ws,
    float* __restrict__ sc_ws, float* __restrict__ tot_ws)
{
    const int bd   = blockIdx.x;
    const int lane = threadIdx.x;
    const size_t sb = (size_t)bd*NCB + lane*4;

    float4 sv = *(const float4*)(sc_ws + sb);
    float l1 = sv.x, l2 = l1 + sv.y, l3 = l2 + sv.z, l4 = l3 + sv.w;
    float inc = l4;
    #pragma unroll
    for (int off = 1; off < 64; off <<= 1) {
        float t = __shfl_up(inc, off);
        if (lane >= off) inc += t;
    }
    float ex = __shfl_up(inc, 1);
    if (lane == 0) ex = 0.0f;
    *(float4*)(sc_ws + sb) = make_float4(ex, ex + l1, ex + l2, ex + l3);
    if (lane == 63) tot_ws[bd] = inc;

    #pragma unroll 1
    for (int n = 0; n < NS; n++) {
        const size_t base = ((size_t)bd*NS + n)*NCB + lane*4;
        float4 av = *(const float4*)(ap_ws + base);
        float4 rv = *(const float4*)(rs_ws + base);
        float Ac = av.x, Bc = rv.x;
        Bc = fmaf(av.y, Bc, rv.y); Ac *= av.y;
        Bc = fmaf(av.z, Bc, rv.z); Ac *= av.z;
        Bc = fmaf(av.w, Bc, rv.w); Ac *= av.w;
        #pragma unroll
        for (int off = 1; off < 64; off <<= 1) {
            float aP = __shfl_up(Ac, off);
            float bP = __shfl_up(Bc, off);
            if (lane >= off) { Bc = fmaf(Ac, bP, Bc); Ac *= aP; }
        }
        float pB = __shfl_up(Bc, 1);
        if (lane == 0) pB = 0.0f;
        float r  = pB;
        float o0 = r; r = fmaf(av.x, r, rv.x);
        float o1 = r; r = fmaf(av.y, r, rv.y);
        float o2 = r; r = fmaf(av.z, r, rv.z);
        float o3 = r;
        *(float4*)(rs_ws + base) = make_float4(o0, o1, o2, o3);
    }
}

// =============== kD: final scan + damp + y (2-deep B/C prefetch) ===============
__global__ __launch_bounds__(320) void kD(
    const h16* __restrict__ dh, const h16* __restrict__ uh,
    const h16* __restrict__ Bh, const h16* __restrict__ Ch,
    const float* __restrict__ A_log, const float* __restrict__ D_param,
    const float* __restrict__ rs_ws, const float* __restrict__ sc_ws,
    const float* __restrict__ tot_ws, float* __restrict__ out)
{
    __shared__ float ylT[20*132];
    const int tid = threadIdx.x;
    const int d   = tid >> 4;
    const int s   = tid & 15;
    const int c   = blockIdx.x;
    const int b   = blockIdx.y;
    const int bd  = b*DI + d;
    const size_t t0 = (size_t)c*TBLK + s*8;

    float d8[8], u8[8], du8[8];
    { half8 hv = *(const half8*)(dh + (size_t)bd*L_ + t0);
      #pragma unroll
      for (int j = 0; j < 8; j++) d8[j] = (float)hv[j]; }
    { half8 hv = *(const half8*)(uh + (size_t)bd*L_ + t0);
      #pragma unroll
      for (int j = 0; j < 8; j++) u8[j] = (float)hv[j]; }
    #pragma unroll
    for (int j = 0; j < 8; j++) du8[j] = d8[j]*u8[j];

    float lp[8];
    { float run = 0.0f;
      #pragma unroll
      for (int j = 0; j < 8; j++) { run += d8[j]; lp[j] = run; } }
    float inc = lp[7];
    SUMSCAN16(inc);
    float ex = dppf<ROW_SHR1>(0.0f, inc);
    const float basep = sc_ws[(size_t)bd*NCB + c] + ex;
    const float Tot   = tot_ws[bd];

    float A_dn[NS], rin[NS];
    #pragma unroll
    for (int n = 0; n < NS; n++) {
        A_dn[n] = -__expf(A_log[d*NS + n]);
        rin[n]  = rs_ws[((size_t)bd*NS + n)*NCB + c];
    }

    float yacc[8];
    #pragma unroll
    for (int j = 0; j < 8; j++) yacc[j] = 0.0f;

    half8 bv0 = *(const half8*)(Bh + (size_t)(b*NS + 0)*L_ + t0);
    half8 cv0 = *(const half8*)(Ch + (size_t)(b*NS + 0)*L_ + t0);
    half8 bv1 = *(const half8*)(Bh + (size_t)(b*NS + 1)*L_ + t0);
    half8 cv1 = *(const half8*)(Ch + (size_t)(b*NS + 1)*L_ + t0);

    #pragma unroll 1
    for (int n = 0; n < NS; n++) {
        half8 bv = bv0, cv = cv0;
        bv0 = bv1; cv0 = cv1;
        if (n + 2 < NS) {
            bv1 = *(const half8*)(Bh + (size_t)(b*NS + n + 2)*L_ + t0);
            cv1 = *(const half8*)(Ch + (size_t)(b*NS + n + 2)*L_ + t0);
        }
        float a8[8], b8[8];
        #pragma unroll
        for (int j = 0; j < 8; j++) {
            a8[j] = __expf(A_dn[n]*d8[j]);
            b8[j] = du8[j]*(float)bv[j];
        }
        float Ac = 1.0f, Bc = 0.0f;
        #pragma unroll
        for (int j = 0; j < 8; j++) { Bc = fmaf(a8[j], Bc, b8[j]); Ac *= a8[j]; }
        OPSCAN16(Ac, Bc);
        float pA = dppf<ROW_SHR1>(1.0f, Ac);
        float pB = dppf<ROW_SHR1>(0.0f, Bc);
        float r  = fmaf(pA, rin[n], pB);

        float G[8];
        G[7] = __expf(A_dn[n]*(Tot - (basep + lp[7])));
        #pragma unroll
        for (int j = 6; j >= 0; j--) G[j] = G[j+1]*a8[j+1];
        #pragma unroll
        for (int j = 0; j < 8; j++) {
            r = fmaf(a8[j], r, b8[j]);
            float damp = G[j] * __builtin_amdgcn_rcpf(G[j] + 1e-12f);
            yacc[j] = fmaf((float)cv[j]*damp, r, yacc[j]);
        }
    }

    const float Dd = D_param[d];
    float yv[8];
    #pragma unroll
    for (int j = 0; j < 8; j++) yv[j] = fmaf(u8[j], Dd, yacc[j]);
    *(float4*)&ylT[d*132 + 8*s]     = *(float4*)(yv);
    *(float4*)&ylT[d*132 + 8*s + 4] = *(float4*)(yv + 4);
    __syncthreads();

    float4* ob4 = (float4*)(out + ((size_t)b*L_ + (size_t)c*TBLK)*DI);
    for (int i = tid; i < TBLK*DI/4; i += 320) {
        int t = i / 5, qq = (i - t*5)*4;
        ob4[i] = make_float4(ylT[qq*132 + t], ylT[(qq+1)*132 + t],
                             ylT[(qq+2)*132 + t], ylT[(qq+3)*132 + t]);
    }
}

extern "C" void kernel_launch(void* const* d_in, const int* in_sizes, int n_in,
                              void* d_out, int out_size, void* d_ws, size_t ws_size,
                              hipStream_t stream) {
    const float* x      = (const float*)d_in[0];
    const float* w_in   = (const float*)d_in[1];
    const float* b_in   = (const float*)d_in[2];
    const float* conv_k = (const float*)d_in[3];
    const float* conv_b = (const float*)d_in[4];
    const float* w_x    = (const float*)d_in[5];
    const float* b_x    = (const float*)d_in[6];
    const float* w_dt   = (const float*)d_in[7];
    const float* b_dt   = (const float*)d_in[8];
    const float* A_log  = (const float*)d_in[9];
    const float* D_par  = (const float*)d_in[10];
    float* out = (float*)d_out;
    float* ws  = (float*)d_ws;

    float* ap_ws  = ws + OFF_AP;
    float* rs_ws  = ws + OFF_RS;
    float* sc_ws  = ws + OFF_SC;
    float* tot_ws = ws + OFF_TOT;
    h16*   hbase  = (h16*)(ws + OFF_H16);
    h16* dh = hbase + HD;
    h16* uh = hbase + HU;
    h16* Bh = hbase + HB;
    h16* Ch = hbase + HC;

    k1<<<dim3(NCB, B_), 320, 0, stream>>>(x, w_in, b_in, conv_k, conv_b,
                                          w_x, b_x, w_dt, b_dt, A_log,
                                          dh, uh, Bh, Ch,
                                          ap_ws, rs_ws, sc_ws);
    kC2<<<B_*DI, 64, 0, stream>>>(ap_ws, rs_ws, sc_ws, tot_ws);
    kD<<<dim3(NCB, B_), 320, 0, stream>>>(dh, uh, Bh, Ch, A_log, D_par,
                                          rs_ws, sc_ws, tot_ws, out);
}

// Round 9
// 130.888 us; speedup vs baseline: 1.1240x; 1.1240x over previous
//
#include <hip/hip_runtime.h>
#include <math.h>

#define B_   4
#define L_   32768
#define DI   20
#define NS   10
#define TBLK 128          // timesteps per chunk/block
#define NCB  256          // chunks per batch

// fp32 summary offsets in ws (floats)
#define OFF_AP  0u
#define OFF_RS  204800u
#define OFF_SC  409600u
#define OFF_TOT 430080u
#define OFF_H16 430160u   // fp16 region starts here
// fp16 offsets (halves)
#define HD  0u            // delta [80][32768]
#define HU  2621440u      // u     [80][32768]
#define HB  5242880u      // B     [40][32768]
#define HC  6553600u      // C     [40][32768]

typedef _Float16 h16;
typedef _Float16 half8 __attribute__((ext_vector_type(8)));
typedef _Float16 half4 __attribute__((ext_vector_type(4)));
typedef float f32x4 __attribute__((ext_vector_type(4)));

// ---- DPP helpers: row_shr within 16-lane rows, OOB lanes -> identity ----
template<int CTRL>
__device__ __forceinline__ float dppf(float idv, float src) {
    union U { float f; int i; };
    U o, s, r; o.f = idv; s.f = src;
    r.i = __builtin_amdgcn_update_dpp(o.i, s.i, CTRL, 0xf, 0xf, false);
    return r.f;
}
#define ROW_SHR1 0x111
#define ROW_SHR2 0x112
#define ROW_SHR4 0x114
#define ROW_SHR8 0x118

#define OPSCAN16(Ac, Bc) \
    { float aP = dppf<ROW_SHR1>(1.0f, Ac); float bP = dppf<ROW_SHR1>(0.0f, Bc); \
      Bc = fmaf(Ac, bP, Bc); Ac *= aP; \
      aP = dppf<ROW_SHR2>(1.0f, Ac); bP = dppf<ROW_SHR2>(0.0f, Bc); \
      Bc = fmaf(Ac, bP, Bc); Ac *= aP; \
      aP = dppf<ROW_SHR4>(1.0f, Ac); bP = dppf<ROW_SHR4>(0.0f, Bc); \
      Bc = fmaf(Ac, bP, Bc); Ac *= aP; \
      aP = dppf<ROW_SHR8>(1.0f, Ac); bP = dppf<ROW_SHR8>(0.0f, Bc); \
      Bc = fmaf(Ac, bP, Bc); Ac *= aP; }

#define SUMSCAN16(v) \
    { v += dppf<ROW_SHR1>(0.0f, v); v += dppf<ROW_SHR2>(0.0f, v); \
      v += dppf<ROW_SHR4>(0.0f, v); v += dppf<ROW_SHR8>(0.0f, v); }

// ---- k1 LDS layout (halves), total 7948 h16 = 15896 B ----
#define XS_   0
#define WST   2864
#define MT_   2864
#define UL_   0
#define XP5_  4608
#define DS__  0
#define CS_   2720
#define BS_   5440   // B staging [10][136] = 1360
#define WX_   6800   // WxT [25][40] = 1000
#define WDTo  7800   // 100
#define BDTo  7900   // 20
#define BXo   7920   // 25
#define POOLH 7948

// =============== k1: MFMA front-end + chunk-local scan ===============
__global__ __launch_bounds__(320) void k1(
    const float* __restrict__ x, const float* __restrict__ w_in,
    const float* __restrict__ b_in, const float* __restrict__ conv_k,
    const float* __restrict__ conv_b, const float* __restrict__ w_x,
    const float* __restrict__ b_x, const float* __restrict__ w_dt,
    const float* __restrict__ b_dt, const float* __restrict__ A_log,
    h16* __restrict__ dh, h16* __restrict__ uh,
    h16* __restrict__ Bh, h16* __restrict__ Ch,
    float* __restrict__ ap_ws, float* __restrict__ rs_ws, float* __restrict__ sc_ws)
{
    __shared__ __align__(16) h16 P[POOLH];
    __shared__ float beff_s[20];

    const int tid = threadIdx.x;
    const int c   = blockIdx.x;
    const int b   = blockIdx.y;
    const int l0  = c * TBLK;

    // ---------- P0: stage weights + x (fp16) ----------
    for (int i = tid; i < 400;  i += 320) P[WST + i]       = (h16)w_in[(i/20)*40 + (i%20)];
    for (int i = tid; i < 1200; i += 320) P[WST + 400 + i] = (h16)conv_k[i];
    for (int i = tid; i < 1000; i += 320) {
        int j = i / 40, k = i - j*40;
        P[WX_ + i] = (k < 20) ? (h16)w_x[k*25 + j] : (h16)0.0f;
    }
    for (int i = tid; i < 100; i += 320) P[WDTo + i] = (h16)w_dt[i];
    if (tid < 20) P[BDTo + tid] = (h16)b_dt[tid];
    if (tid < 25) P[BXo  + tid] = (h16)b_x[tid];
    for (int idx = tid; idx < 130*20; idx += 320) {
        int p = idx / 20, i = idx - p*20;
        int l = l0 - 2 + p;
        P[XS_ + p*22 + i] = (l >= 0) ? (h16)x[((size_t)b*L_ + l)*DI + i] : (h16)0.0f;
    }
    __syncthreads();

    // ---------- P1: Meff = w_in @ conv_k (per tap), beff ----------
    float me[4]; int mei[4];
    #pragma unroll
    for (int r = 0; r < 4; r++) {
        int e = tid + r*320;
        float acc = 0.0f;
        if (e < 1200) {
            int cc = e / 20, o = e - cc*20;
            int w = cc / 20, i = cc - w*20;
            #pragma unroll
            for (int op = 0; op < 20; op++)
                acc = fmaf((float)P[WST + i*20 + op],
                           (float)P[WST + 400 + (w*20 + op)*20 + o], acc);
        }
        me[r] = acc; mei[r] = e;
    }
    float be = 0.0f;
    if (tid < 20) {
        be = conv_b[tid];
        #pragma unroll
        for (int w = 0; w < 3; w++)
            #pragma unroll
            for (int op = 0; op < 20; op++)
                be = fmaf(b_in[op], (float)P[WST + 400 + (w*20 + op)*20 + tid], be);
    }
    __syncthreads();
    #pragma unroll
    for (int r = 0; r < 4; r++) {
        int e = mei[r];
        if (e < 1200) {
            int cc = e / 20, o = e - cc*20;
            P[MT_ + o*68 + cc] = (h16)me[r];
        }
    }
    if (tid < 20) beff_s[tid] = be;
    __syncthreads();

    // ---------- P2: u_pre = Xwin @ Meff (MFMA), +beff, silu ----------
    const int wv  = tid >> 6;
    const int ln  = tid & 63;
    const int m16 = ln & 15;
    const int q   = ln >> 4;
    float uval[4][4];
    if (wv < 4) {
        #pragma unroll
        for (int jj = 0; jj < 4; jj++) {
            int job = wv*4 + jj, mt = job >> 1, nt = job & 1;
            int t_row = mt*16 + m16;
            int dcol  = nt*16 + m16;
            int dmin  = dcol < 20 ? dcol : 19;
            f32x4 acc = {0.0f, 0.0f, 0.0f, 0.0f};
            #pragma unroll
            for (int kh = 0; kh < 2; kh++) {
                half8 af;
                #pragma unroll
                for (int j = 0; j < 8; j++) {
                    int k = kh*32 + (q<<3) + j;
                    int w = (k >= 20) + (k >= 40);
                    int i = k - 20*w;
                    af[j] = (k < 60) ? P[XS_ + (t_row + w)*22 + i] : (h16)0.0f;
                }
                half8 bf;
                *(half4*)&bf    = *(const half4*)&P[MT_ + dmin*68 + kh*32 + (q<<3)];
                *((half4*)&bf+1)= *(const half4*)&P[MT_ + dmin*68 + kh*32 + (q<<3) + 4];
                acc = __builtin_amdgcn_mfma_f32_16x16x32_f16(af, bf, acc, 0, 0, 0);
            }
            float bf2 = beff_s[dmin];
            #pragma unroll
            for (int r = 0; r < 4; r++) {
                float a = acc[r] + bf2;
                uval[jj][r] = a / (1.0f + __expf(-a));
            }
        }
    }
    __syncthreads();   // xs/MeffT dead -> UL may overwrite
    if (wv < 4) {
        #pragma unroll
        for (int jj = 0; jj < 4; jj++) {
            int job = wv*4 + jj, mt = job >> 1, nt = job & 1;
            int dcol = nt*16 + m16;
            if (dcol < 20) {
                #pragma unroll
                for (int r = 0; r < 4; r++)
                    P[UL_ + (mt*16 + q*4 + r)*36 + dcol] = (h16)uval[jj][r];
            }
        }
    }
    for (int i = tid; i < 128*12; i += 320) {
        int t = i / 12, z = i - t*12;
        P[UL_ + t*36 + 20 + z] = (h16)0.0f;
    }
    __syncthreads();

    // ---------- P3: xp = u @ w_x (MFMA), +b_x ----------
    float xv[4][4];
    if (wv < 4) {
        #pragma unroll
        for (int jj = 0; jj < 4; jj++) {
            int job = wv*4 + jj, mt = job >> 1, nt = job & 1;
            int t_row = mt*16 + m16;
            int j     = nt*16 + m16;
            int jmin  = j < 25 ? j : 24;
            f32x4 acc = {0.0f, 0.0f, 0.0f, 0.0f};
            half8 af;
            *(half4*)&af     = *(const half4*)&P[UL_ + t_row*36 + (q<<3)];
            *((half4*)&af+1) = *(const half4*)&P[UL_ + t_row*36 + (q<<3) + 4];
            half8 bf = *(const half8*)&P[WX_ + jmin*40 + (q<<3)];
            acc = __builtin_amdgcn_mfma_f32_16x16x32_f16(af, bf, acc, 0, 0, 0);
            float bx = (j < 25) ? (float)P[BXo + j] : 0.0f;
            #pragma unroll
            for (int r = 0; r < 4; r++) xv[jj][r] = acc[r] + bx;
        }
        #pragma unroll
        for (int jj = 0; jj < 4; jj++) {
            int job = wv*4 + jj, nt = job & 1, mt = job >> 1;
            int j = nt*16 + m16;
            #pragma unroll
            for (int r = 0; r < 4; r++) {
                int t_out = mt*16 + q*4 + r;
                if (j < 5)            P[XP5_ + t_out*5 + j]        = (h16)xv[jj][r];
                else if (j < 15)      P[BS_ + (j - 5)*136 + t_out] = (h16)xv[jj][r];
            }
        }
    }
    __syncthreads();

    // ---------- P4b: scan u8 loads (UL); t-threads: uh/Bh coalesced + softmax ----
    const int d  = tid >> 4;
    const int s  = tid & 15;
    const int bd = b*DI + d;

    float u8[8];
    #pragma unroll
    for (int j = 0; j < 8; j++) u8[j] = (float)P[UL_ + (8*s + j)*36 + d];

    float dl[20];
    if (tid < 128) {
        const int t = tid;
        #pragma unroll
        for (int d2 = 0; d2 < 20; d2++)
            uh[(size_t)(b*DI + d2)*L_ + l0 + t] = P[UL_ + t*36 + d2];
        #pragma unroll
        for (int n = 0; n < NS; n++)
            Bh[(size_t)(b*NS + n)*L_ + l0 + t] = P[BS_ + n*136 + t];
        float xq[5];
        #pragma unroll
        for (int r = 0; r < 5; r++) xq[r] = (float)P[XP5_ + t*5 + r];
        #pragma unroll
        for (int d2 = 0; d2 < 20; d2++) dl[d2] = (float)P[BDTo + d2];
        #pragma unroll
        for (int r = 0; r < 5; r++) {
            float dv = xq[r];
            #pragma unroll
            for (int d2 = 0; d2 < 20; d2++)
                dl[d2] = fmaf(dv, (float)P[WDTo + r*20 + d2], dl[d2]);
        }
        float mx = dl[0];
        #pragma unroll
        for (int d2 = 1; d2 < 20; d2++) mx = fmaxf(mx, dl[d2]);
        float sm = 0.0f;
        #pragma unroll
        for (int d2 = 0; d2 < 20; d2++) { dl[d2] = __expf(dl[d2] - mx); sm += dl[d2]; }
        float inv = 1.0f / sm;
        #pragma unroll
        for (int d2 = 0; d2 < 20; d2++) dl[d2] *= inv;
    }
    __syncthreads();   // UL/xp5 dead

    // ---------- P4c: DS + dh writes; CS from xv regs ----------
    if (tid < 128) {
        const int t = tid;
        #pragma unroll
        for (int d2 = 0; d2 < 20; d2++) {
            h16 dlh = (h16)dl[d2];
            P[DS__ + d2*136 + t] = dlh;
            dh[(size_t)(b*DI + d2)*L_ + l0 + t] = dlh;
        }
    }
    if (wv < 4) {
        #pragma unroll
        for (int jj = 0; jj < 4; jj++) {
            int job = wv*4 + jj, nt = job & 1, mt = job >> 1;
            int j = nt*16 + m16;
            if (j >= 15 && j < 25) {
                #pragma unroll
                for (int r = 0; r < 4; r++)
                    P[CS_ + (j - 15)*136 + (mt*16 + q*4 + r)] = (h16)xv[jj][r];
            }
        }
    }
    __syncthreads();

    // ---------- P4d: Ch coalesced; scan d8 ----------
    if (tid < 128) {
        const int t = tid;
        #pragma unroll
        for (int n = 0; n < NS; n++)
            Ch[(size_t)(b*NS + n)*L_ + l0 + t] = P[CS_ + n*136 + t];
    }
    float d8[8], du8[8];
    { half8 hv = *(const half8*)&P[DS__ + d*136 + 8*s];
      #pragma unroll
      for (int j = 0; j < 8; j++) d8[j] = (float)hv[j]; }
    #pragma unroll
    for (int j = 0; j < 8; j++) du8[j] = d8[j]*u8[j];

    // ---------- P5: chunk-local scan ----------
    float ssum = 0.0f;
    #pragma unroll
    for (int j = 0; j < 8; j++) ssum += d8[j];
    SUMSCAN16(ssum);
    if (s == 15) sc_ws[(size_t)bd*NCB + c] = ssum;

    float A_dn[NS];
    #pragma unroll
    for (int n = 0; n < NS; n++) A_dn[n] = -__expf(A_log[d*NS + n]);

    #pragma unroll 1
    for (int n = 0; n < NS; n++) {
        half8 bv = *(const half8*)&P[BS_ + n*136 + 8*s];
        float Ac = 1.0f, Bc = 0.0f;
        #pragma unroll
        for (int j = 0; j < 8; j++) {
            float a = __expf(A_dn[n]*d8[j]);
            Bc = fmaf(a, Bc, du8[j]*(float)bv[j]);
            Ac *= a;
        }
        OPSCAN16(Ac, Bc);
        if (s == 15) {
            size_t o = ((size_t)bd*NS + n)*NCB + c;
            ap_ws[o] = Ac;
            rs_ws[o] = Bc;
        }
    }
}

// =============== kC2: inter-chunk scan (one wave per (b,d)) ===============
__global__ __launch_bounds__(64) void kC2(
    const float* __restrict__ ap_ws, float* __restrict__ rs_ws,
    float* __restrict__ sc_ws, float* __restrict__ tot_ws)
{
    const int bd   = blockIdx.x;
    const int lane = threadIdx.x;
    const size_t sb = (size_t)bd*NCB + lane*4;

    float4 sv = *(const float4*)(sc_ws + sb);
    float l1 = sv.x, l2 = l1 + sv.y, l3 = l2 + sv.z, l4 = l3 + sv.w;
    float inc = l4;
    #pragma unroll
    for (int off = 1; off < 64; off <<= 1) {
        float t = __shfl_up(inc, off);
        if (lane >= off) inc += t;
    }
    float ex = __shfl_up(inc, 1);
    if (lane == 0) ex = 0.0f;
    *(float4*)(sc_ws + sb) = make_float4(ex, ex + l1, ex + l2, ex + l3);
    if (lane == 63) tot_ws[bd] = inc;

    #pragma unroll 1
    for (int n = 0; n < NS; n++) {
        const size_t base = ((size_t)bd*NS + n)*NCB + lane*4;
        float4 av = *(const float4*)(ap_ws + base);
        float4 rv = *(const float4*)(rs_ws + base);
        float Ac = av.x, Bc = rv.x;
        Bc = fmaf(av.y, Bc, rv.y); Ac *= av.y;
        Bc = fmaf(av.z, Bc, rv.z); Ac *= av.z;
        Bc = fmaf(av.w, Bc, rv.w); Ac *= av.w;
        #pragma unroll
        for (int off = 1; off < 64; off <<= 1) {
            float aP = __shfl_up(Ac, off);
            float bP = __shfl_up(Bc, off);
            if (lane >= off) { Bc = fmaf(Ac, bP, Bc); Ac *= aP; }
        }
        float pB = __shfl_up(Bc, 1);
        if (lane == 0) pB = 0.0f;
        float r  = pB;
        float o0 = r; r = fmaf(av.x, r, rv.x);
        float o1 = r; r = fmaf(av.y, r, rv.y);
        float o2 = r; r = fmaf(av.z, r, rv.z);
        float o3 = r;
        *(float4*)(rs_ws + base) = make_float4(o0, o1, o2, o3);
    }
}

// =============== kD: damp-gated final scan + y ===============
// Chunks whose entire damp factor is < ~4e-6 (i.e. A_max*(Tot - pref_end) < -40)
// contribute y = u*D exactly (to well below threshold) -> skip the scan.
__global__ __launch_bounds__(320) void kD(
    const h16* __restrict__ dh, const h16* __restrict__ uh,
    const h16* __restrict__ Bh, const h16* __restrict__ Ch,
    const float* __restrict__ A_log, const float* __restrict__ D_param,
    const float* __restrict__ rs_ws, const float* __restrict__ sc_ws,
    const float* __restrict__ tot_ws, float* __restrict__ out)
{
    __shared__ float ylT[20*132];
    const int tid = threadIdx.x;
    const int d   = tid >> 4;
    const int s   = tid & 15;
    const int c   = blockIdx.x;
    const int b   = blockIdx.y;
    const int bd  = b*DI + d;
    const size_t t0 = (size_t)c*TBLK + s*8;

    const float Tot = tot_ws[bd];
    float A_dn[NS];
    float Amax = -1e30f;
    #pragma unroll
    for (int n = 0; n < NS; n++) {
        A_dn[n] = -__expf(A_log[d*NS + n]);
        Amax = fmaxf(Amax, A_dn[n]);
    }
    // exclusive prefix at END of this chunk (= prefix before chunk c+1)
    const float pref_end = (c + 1 < NCB) ? sc_ws[(size_t)bd*NCB + c + 1] : Tot;
    const bool active = fmaf(Amax, Tot - pref_end, 40.0f) > 0.0f;

    float u8[8];
    { half8 hv = *(const half8*)(uh + (size_t)bd*L_ + t0);
      #pragma unroll
      for (int j = 0; j < 8; j++) u8[j] = (float)hv[j]; }
    const float Dd = D_param[d];
    float yv[8];
    #pragma unroll
    for (int j = 0; j < 8; j++) yv[j] = u8[j]*Dd;

    if (active) {
        float d8[8], du8[8];
        { half8 hv = *(const half8*)(dh + (size_t)bd*L_ + t0);
          #pragma unroll
          for (int j = 0; j < 8; j++) d8[j] = (float)hv[j]; }
        #pragma unroll
        for (int j = 0; j < 8; j++) du8[j] = d8[j]*u8[j];

        float lp[8];
        { float run = 0.0f;
          #pragma unroll
          for (int j = 0; j < 8; j++) { run += d8[j]; lp[j] = run; } }
        float inc = lp[7];
        SUMSCAN16(inc);
        float ex = dppf<ROW_SHR1>(0.0f, inc);
        const float basep = sc_ws[(size_t)bd*NCB + c] + ex;

        float rin[NS];
        #pragma unroll
        for (int n = 0; n < NS; n++) rin[n] = rs_ws[((size_t)bd*NS + n)*NCB + c];

        float yacc[8];
        #pragma unroll
        for (int j = 0; j < 8; j++) yacc[j] = 0.0f;

        half8 bv0 = *(const half8*)(Bh + (size_t)(b*NS + 0)*L_ + t0);
        half8 cv0 = *(const half8*)(Ch + (size_t)(b*NS + 0)*L_ + t0);
        half8 bv1 = *(const half8*)(Bh + (size_t)(b*NS + 1)*L_ + t0);
        half8 cv1 = *(const half8*)(Ch + (size_t)(b*NS + 1)*L_ + t0);

        #pragma unroll 1
        for (int n = 0; n < NS; n++) {
            half8 bv = bv0, cv = cv0;
            bv0 = bv1; cv0 = cv1;
            if (n + 2 < NS) {
                bv1 = *(const half8*)(Bh + (size_t)(b*NS + n + 2)*L_ + t0);
                cv1 = *(const half8*)(Ch + (size_t)(b*NS + n + 2)*L_ + t0);
            }
            float a8[8], b8[8];
            #pragma unroll
            for (int j = 0; j < 8; j++) {
                a8[j] = __expf(A_dn[n]*d8[j]);
                b8[j] = du8[j]*(float)bv[j];
            }
            float Ac = 1.0f, Bc = 0.0f;
            #pragma unroll
            for (int j = 0; j < 8; j++) { Bc = fmaf(a8[j], Bc, b8[j]); Ac *= a8[j]; }
            OPSCAN16(Ac, Bc);
            float pA = dppf<ROW_SHR1>(1.0f, Ac);
            float pB = dppf<ROW_SHR1>(0.0f, Bc);
            float r  = fmaf(pA, rin[n], pB);

            float G[8];
            G[7] = __expf(A_dn[n]*(Tot - (basep + lp[7])));
            #pragma unroll
            for (int j = 6; j >= 0; j--) G[j] = G[j+1]*a8[j+1];
            #pragma unroll
            for (int j = 0; j < 8; j++) {
                r = fmaf(a8[j], r, b8[j]);
                float damp = G[j] * __builtin_amdgcn_rcpf(G[j] + 1e-12f);
                yacc[j] = fmaf((float)cv[j]*damp, r, yacc[j]);
            }
        }
        #pragma unroll
        for (int j = 0; j < 8; j++) yv[j] = fmaf(u8[j], Dd, yacc[j]);
    }

    *(float4*)&ylT[d*132 + 8*s]     = *(float4*)(yv);
    *(float4*)&ylT[d*132 + 8*s + 4] = *(float4*)(yv + 4);
    __syncthreads();

    float4* ob4 = (float4*)(out + ((size_t)b*L_ + (size_t)c*TBLK)*DI);
    for (int i = tid; i < TBLK*DI/4; i += 320) {
        int t = i / 5, qq = (i - t*5)*4;
        ob4[i] = make_float4(ylT[qq*132 + t], ylT[(qq+1)*132 + t],
                             ylT[(qq+2)*132 + t], ylT[(qq+3)*132 + t]);
    }
}

extern "C" void kernel_launch(void* const* d_in, const int* in_sizes, int n_in,
                              void* d_out, int out_size, void* d_ws, size_t ws_size,
                              hipStream_t stream) {
    const float* x      = (const float*)d_in[0];
    const float* w_in   = (const float*)d_in[1];
    const float* b_in   = (const float*)d_in[2];
    const float* conv_k = (const float*)d_in[3];
    const float* conv_b = (const float*)d_in[4];
    const float* w_x    = (const float*)d_in[5];
    const float* b_x    = (const float*)d_in[6];
    const float* w_dt   = (const float*)d_in[7];
    const float* b_dt   = (const float*)d_in[8];
    const float* A_log  = (const float*)d_in[9];
    const float* D_par  = (const float*)d_in[10];
    float* out = (float*)d_out;
    float* ws  = (float*)d_ws;

    float* ap_ws  = ws + OFF_AP;
    float* rs_ws  = ws + OFF_RS;
    float* sc_ws  = ws + OFF_SC;
    float* tot_ws = ws + OFF_TOT;
    h16*   hbase  = (h16*)(ws + OFF_H16);
    h16* dh = hbase + HD;
    h16* uh = hbase + HU;
    h16* Bh = hbase + HB;
    h16* Ch = hbase + HC;

    k1<<<dim3(NCB, B_), 320, 0, stream>>>(x, w_in, b_in, conv_k, conv_b,
                                          w_x, b_x, w_dt, b_dt, A_log,
                                          dh, uh, Bh, Ch,
                                          ap_ws, rs_ws, sc_ws);
    kC2<<<B_*DI, 64, 0, stream>>>(ap_ws, rs_ws, sc_ws, tot_ws);
    kD<<<dim3(NCB, B_), 320, 0, stream>>>(dh, uh, Bh, Ch, A_log, D_par,
                                          rs_ws, sc_ws, tot_ws, out);
}

// Round 10
// 125.008 us; speedup vs baseline: 1.1769x; 1.0470x over previous
//
#include <hip/hip_runtime.h>
#include <math.h>

#define B_   4
#define L_   32768
#define DI   20
#define NS   10
#define TBLK 128          // timesteps per chunk/block
#define NCB  256          // chunks per batch

// fp32 offsets in ws (floats)
#define OFF_AP   0u
#define OFF_RS   204800u
#define OFF_SC   409600u
#define OFF_TOT  430080u
#define OFF_BEFF 430160u   // 20 floats
#define OFF_H16  430192u   // h16 region (16B aligned)
// half offsets within h16 region
#define HD  0u             // delta [80][32768]
#define HU  2621440u       // u
#define HB  5242880u       // B [40][32768]
#define HC  6553600u       // C
#define HW  7864320u       // preformatted weights (2585 halves)
// weight block sub-offsets (halves)
#define WMT 0              // MeffT [20][72], cols 60..71 = 0
#define WWX 1440           // WxT   [25][40], cols 20..39 = 0
#define WWD 2440           // w_dt  100
#define WBD 2540           // b_dt  20
#define WBX 2560           // b_x   25

typedef _Float16 h16;
typedef _Float16 half8 __attribute__((ext_vector_type(8)));
typedef _Float16 half4 __attribute__((ext_vector_type(4)));
typedef float f32x4 __attribute__((ext_vector_type(4)));

// ---- DPP helpers: row_shr within 16-lane rows, OOB lanes -> identity ----
template<int CTRL>
__device__ __forceinline__ float dppf(float idv, float src) {
    union U { float f; int i; };
    U o, s, r; o.f = idv; s.f = src;
    r.i = __builtin_amdgcn_update_dpp(o.i, s.i, CTRL, 0xf, 0xf, false);
    return r.f;
}
#define ROW_SHR1 0x111
#define ROW_SHR2 0x112
#define ROW_SHR4 0x114
#define ROW_SHR8 0x118

#define OPSCAN16(Ac, Bc) \
    { float aP = dppf<ROW_SHR1>(1.0f, Ac); float bP = dppf<ROW_SHR1>(0.0f, Bc); \
      Bc = fmaf(Ac, bP, Bc); Ac *= aP; \
      aP = dppf<ROW_SHR2>(1.0f, Ac); bP = dppf<ROW_SHR2>(0.0f, Bc); \
      Bc = fmaf(Ac, bP, Bc); Ac *= aP; \
      aP = dppf<ROW_SHR4>(1.0f, Ac); bP = dppf<ROW_SHR4>(0.0f, Bc); \
      Bc = fmaf(Ac, bP, Bc); Ac *= aP; \
      aP = dppf<ROW_SHR8>(1.0f, Ac); bP = dppf<ROW_SHR8>(0.0f, Bc); \
      Bc = fmaf(Ac, bP, Bc); Ac *= aP; }

#define SUMSCAN16(v) \
    { v += dppf<ROW_SHR1>(0.0f, v); v += dppf<ROW_SHR2>(0.0f, v); \
      v += dppf<ROW_SHR4>(0.0f, v); v += dppf<ROW_SHR8>(0.0f, v); }

// ---- k1 LDS layout (halves), POOLH = 7956 (15912 B) ----
// XS  0..2640      flat x window, stride 20 (P0->P2); tail 2600..2639 zeroed
// MT  2640..4080   MeffT stride 72 (P0->P2)
// UL  0..4608      u, stride 36, cols 20..31 zero (after b2 -> b5)
// DS  0..2720      delta [20][136] (after b5)
// DUS 2720..5440   delta*u [20][136] (after b5)
// XP5 4608..5248   xp cols 0..4, stride 5 (P3 -> b5)
// BS  5448..6808   B staging [10][136] (P3 -> end)
// WX  6808..7808   WxT stride 40 (P0 -> P3)
// WDT 7808..7908 | BDT 7908..7928 | BX 7928..7953
#define XS_   0
#define MT_   2640
#define UL_   0
#define DS__  0
#define DUS_  2720
#define XP5_  4608
#define BS_   5448
#define WXo   6808
#define WDTo  7808
#define BDTo  7908
#define BXo   7928
#define POOLH 7956

// =============== k0: one-block weight preformatting ===============
__global__ __launch_bounds__(320) void k0(
    const float* __restrict__ w_in, const float* __restrict__ b_in,
    const float* __restrict__ conv_k, const float* __restrict__ conv_b,
    const float* __restrict__ w_x, const float* __restrict__ w_dt,
    const float* __restrict__ b_dt, const float* __restrict__ b_x,
    h16* __restrict__ wts, float* __restrict__ beff)
{
    __shared__ float W[1600];   // w_in 20x20 @0, conv_k @400
    const int tid = threadIdx.x;
    for (int i = tid; i < 400;  i += 320) W[i]       = w_in[(i/20)*40 + (i%20)];
    for (int i = tid; i < 1200; i += 320) W[400 + i] = conv_k[i];
    __syncthreads();
    for (int e = tid; e < 1200; e += 320) {
        int cc = e/20, o = e - cc*20;
        int w = cc/20, i = cc - w*20;
        float acc = 0.0f;
        #pragma unroll
        for (int op = 0; op < 20; op++)
            acc = fmaf(W[i*20 + op], W[400 + (w*20 + op)*20 + o], acc);
        wts[WMT + o*72 + cc] = (h16)acc;
    }
    for (int i = tid; i < 240; i += 320) {          // zero MT cols 60..71
        int o = i/12, cc = 60 + (i - (i/12)*12);
        wts[WMT + o*72 + cc] = (h16)0.0f;
    }
    for (int i = tid; i < 1000; i += 320) {         // WxT[j][k=d]
        int j = i/40, k = i - j*40;
        wts[WWX + i] = (k < 20) ? (h16)w_x[k*25 + j] : (h16)0.0f;
    }
    for (int i = tid; i < 100; i += 320) wts[WWD + i] = (h16)w_dt[i];
    if (tid < 20) wts[WBD + tid] = (h16)b_dt[tid];
    if (tid < 25) wts[WBX + tid] = (h16)b_x[tid];
    if (tid < 20) {
        float be = conv_b[tid];
        #pragma unroll
        for (int w = 0; w < 3; w++)
            #pragma unroll
            for (int op = 0; op < 20; op++)
                be = fmaf(b_in[op], W[400 + (w*20 + op)*20 + tid], be);
        beff[tid] = be;
    }
}

// =============== k1: MFMA front-end + chunk-local scan ===============
__global__ __launch_bounds__(320) void k1(
    const float* __restrict__ x, const h16* __restrict__ wts,
    const float* __restrict__ beff, const float* __restrict__ A_log,
    h16* __restrict__ dh, h16* __restrict__ uh,
    h16* __restrict__ Bh, h16* __restrict__ Ch,
    float* __restrict__ ap_ws, float* __restrict__ rs_ws, float* __restrict__ sc_ws)
{
    __shared__ __align__(16) h16 P[POOLH];
    __shared__ float beff_s[20];

    const int tid = threadIdx.x;
    const int c   = blockIdx.x;
    const int b   = blockIdx.y;
    const int l0  = c * TBLK;

    // ---------- P0: copy preformatted weights + flat x window ----------
    {
        const int* src = (const int*)(wts + WMT);     // 1440 halves = 720 ints
        int* dst = (int*)&P[MT_];
        for (int i = tid; i < 720; i += 320) dst[i] = src[i];
        const int* s2 = (const int*)(wts + WWX);      // 1145 halves
        int* d2 = (int*)&P[WXo];
        for (int i = tid; i < 572; i += 320) d2[i] = s2[i];
        if (tid == 0) P[WXo + 1144] = wts[WWX + 1144];
        if (tid < 20) beff_s[tid] = beff[tid];
    }
    {
        const float* xb = x + ((size_t)b*L_ + l0)*DI - 2*DI;
        for (int i = tid; i < 1320; i += 320) {
            float2 v;
            if (i >= 1300 || (c == 0 && i < 20)) v = make_float2(0.0f, 0.0f);
            else v = *(const float2*)(xb + 2*i);
            P[XS_ + 2*i]     = (h16)v.x;
            P[XS_ + 2*i + 1] = (h16)v.y;
        }
    }
    __syncthreads();

    // ---------- P2: u_pre = Xflat @ Meff (MFMA), +beff, silu ----------
    const int wv  = tid >> 6;
    const int ln  = tid & 63;
    const int m16 = ln & 15;
    const int q   = ln >> 4;
    float uval[4][4];
    if (wv < 4) {
        #pragma unroll
        for (int jj = 0; jj < 4; jj++) {
            int job = wv*4 + jj, mt = job >> 1, nt = job & 1;
            int t_row = mt*16 + m16;
            int dcol  = nt*16 + m16;
            int dmin  = dcol < 20 ? dcol : 19;
            f32x4 acc = {0.0f, 0.0f, 0.0f, 0.0f};
            #pragma unroll
            for (int kh = 0; kh < 2; kh++) {
                half8 af, bf;
                int ab = XS_ + t_row*20 + kh*32 + (q<<3);
                *(half4*)&af         = *(const half4*)&P[ab];
                *(((half4*)&af) + 1) = *(const half4*)&P[ab + 4];
                int bb = MT_ + dmin*72 + kh*32 + (q<<3);
                *(half4*)&bf         = *(const half4*)&P[bb];
                *(((half4*)&bf) + 1) = *(const half4*)&P[bb + 4];
                acc = __builtin_amdgcn_mfma_f32_16x16x32_f16(af, bf, acc, 0, 0, 0);
            }
            float bfv = beff_s[dmin];
            #pragma unroll
            for (int r = 0; r < 4; r++) {
                float a = acc[r] + bfv;
                uval[jj][r] = a * __builtin_amdgcn_rcpf(1.0f + __expf(-a));
            }
        }
    }
    __syncthreads();   // b2: XS/MT dead -> UL may overwrite

    if (wv < 4) {
        #pragma unroll
        for (int jj = 0; jj < 4; jj++) {
            int job = wv*4 + jj, mt = job >> 1, nt = job & 1;
            int dcol = nt*16 + m16;
            if (dcol < 20) {
                #pragma unroll
                for (int r = 0; r < 4; r++)
                    P[UL_ + (mt*16 + q*4 + r)*36 + dcol] = (h16)uval[jj][r];
            }
        }
    }
    for (int i = tid; i < 1536; i += 320) {   // zero UL cols 20..31 (A k-pad)
        int t = i/12, z = i - t*12;
        P[UL_ + t*36 + 20 + z] = (h16)0.0f;
    }
    __syncthreads();   // b3

    // ---------- P3: xp = u @ w_x (MFMA), +b_x; stash XP5/BS; Ch direct ----------
    float xv[4][4];
    if (wv < 4) {
        #pragma unroll
        for (int jj = 0; jj < 4; jj++) {
            int job = wv*4 + jj, mt = job >> 1, nt = job & 1;
            int t_row = mt*16 + m16;
            int j     = nt*16 + m16;
            int jmin  = j < 25 ? j : 24;
            f32x4 acc = {0.0f, 0.0f, 0.0f, 0.0f};
            half8 af, bf;
            int ab = UL_ + t_row*36 + (q<<3);
            *(half4*)&af         = *(const half4*)&P[ab];
            *(((half4*)&af) + 1) = *(const half4*)&P[ab + 4];
            int bb = WXo + jmin*40 + (q<<3);
            *(half4*)&bf         = *(const half4*)&P[bb];
            *(((half4*)&bf) + 1) = *(const half4*)&P[bb + 4];
            acc = __builtin_amdgcn_mfma_f32_16x16x32_f16(af, bf, acc, 0, 0, 0);
            float bx = (j < 25) ? (float)P[BXo + j] : 0.0f;
            #pragma unroll
            for (int r = 0; r < 4; r++) xv[jj][r] = acc[r] + bx;
        }
        #pragma unroll
        for (int jj = 0; jj < 4; jj++) {
            int job = wv*4 + jj, mt = job >> 1, nt = job & 1;
            int j = nt*16 + m16;
            #pragma unroll
            for (int r = 0; r < 4; r++) {
                int t = mt*16 + q*4 + r;
                h16 hv = (h16)xv[jj][r];
                if (j < 5)       P[XP5_ + t*5 + j] = hv;
                else if (j < 15) P[BS_ + (j - 5)*136 + t] = hv;
                else if (j < 25) Ch[(size_t)(b*NS + (j - 15))*L_ + l0 + t] = hv;
            }
        }
    }
    __syncthreads();   // b4

    // ---------- P4b: t-threads: uh+Bh coalesced, softmax (u row kept in regs) ----
    h16 urow[20];
    float dl[20];
    if (tid < 128) {
        const int t = tid;
        *(half4*)&urow[0]  = *(const half4*)&P[UL_ + t*36 + 0];
        *(half4*)&urow[4]  = *(const half4*)&P[UL_ + t*36 + 4];
        *(half4*)&urow[8]  = *(const half4*)&P[UL_ + t*36 + 8];
        *(half4*)&urow[12] = *(const half4*)&P[UL_ + t*36 + 12];
        *(half4*)&urow[16] = *(const half4*)&P[UL_ + t*36 + 16];
        #pragma unroll
        for (int d2 = 0; d2 < 20; d2++)
            uh[(size_t)(b*DI + d2)*L_ + l0 + t] = urow[d2];
        #pragma unroll
        for (int n = 0; n < NS; n++)
            Bh[(size_t)(b*NS + n)*L_ + l0 + t] = P[BS_ + n*136 + t];
        float xq[5];
        #pragma unroll
        for (int r = 0; r < 5; r++) xq[r] = (float)P[XP5_ + t*5 + r];
        #pragma unroll
        for (int d2 = 0; d2 < 20; d2++) dl[d2] = (float)P[BDTo + d2];
        #pragma unroll
        for (int r = 0; r < 5; r++) {
            float dv = xq[r];
            #pragma unroll
            for (int d2 = 0; d2 < 20; d2++)
                dl[d2] = fmaf(dv, (float)P[WDTo + r*20 + d2], dl[d2]);
        }
        float mx = dl[0];
        #pragma unroll
        for (int d2 = 1; d2 < 20; d2++) mx = fmaxf(mx, dl[d2]);
        float sm = 0.0f;
        #pragma unroll
        for (int d2 = 0; d2 < 20; d2++) { dl[d2] = __expf(dl[d2] - mx); sm += dl[d2]; }
        float inv = __builtin_amdgcn_rcpf(sm);
        #pragma unroll
        for (int d2 = 0; d2 < 20; d2++) dl[d2] *= inv;
    }
    __syncthreads();   // b5: UL/XP5 dead

    // ---------- P4c: DS/DUS staging + dh ----------
    if (tid < 128) {
        const int t = tid;
        #pragma unroll
        for (int d2 = 0; d2 < 20; d2++) {
            h16 dlh = (h16)dl[d2];
            P[DS__ + d2*136 + t] = dlh;
            P[DUS_ + d2*136 + t] = (h16)((float)dlh * (float)urow[d2]);
            dh[(size_t)(b*DI + d2)*L_ + l0 + t] = dlh;
        }
    }
    __syncthreads();   // b6

    // ---------- P5: chunk-local scan (20 d x 16 lanes, 8 t/lane) ----------
    const int d  = tid >> 4;
    const int s  = tid & 15;
    const int bd = b*DI + d;

    float d8[8], du8[8];
    { half8 hv = *(const half8*)&P[DS__ + d*136 + 8*s];
      #pragma unroll
      for (int j = 0; j < 8; j++) d8[j] = (float)hv[j]; }
    { half8 hv = *(const half8*)&P[DUS_ + d*136 + 8*s];
      #pragma unroll
      for (int j = 0; j < 8; j++) du8[j] = (float)hv[j]; }

    float ssum = 0.0f;
    #pragma unroll
    for (int j = 0; j < 8; j++) ssum += d8[j];
    SUMSCAN16(ssum);
    if (s == 15) sc_ws[(size_t)bd*NCB + c] = ssum;

    float A_dn[NS];
    #pragma unroll
    for (int n = 0; n < NS; n++) A_dn[n] = -__expf(A_log[d*NS + n]);

    #pragma unroll 1
    for (int n = 0; n < NS; n++) {
        half8 bv = *(const half8*)&P[BS_ + n*136 + 8*s];
        float Ac = 1.0f, Bc = 0.0f;
        #pragma unroll
        for (int j = 0; j < 8; j++) {
            float a = __expf(A_dn[n]*d8[j]);
            Bc = fmaf(a, Bc, du8[j]*(float)bv[j]);
            Ac *= a;
        }
        OPSCAN16(Ac, Bc);
        if (s == 15) {
            size_t o = ((size_t)bd*NS + n)*NCB + c;
            ap_ws[o] = Ac;
            rs_ws[o] = Bc;
        }
    }
}

// =============== kC2: inter-chunk scan (one wave per (b,d)) ===============
__global__ __launch_bounds__(64) void kC2(
    const float* __restrict__ ap_ws, float* __restrict__ rs_ws,
    float* __restrict__ sc_ws, float* __restrict__ tot_ws)
{
    const int bd   = blockIdx.x;
    const int lane = threadIdx.x;
    const size_t sb = (size_t)bd*NCB + lane*4;

    float4 sv = *(const float4*)(sc_ws + sb);
    float l1 = sv.x, l2 = l1 + sv.y, l3 = l2 + sv.z, l4 = l3 + sv.w;
    float inc = l4;
    #pragma unroll
    for (int off = 1; off < 64; off <<= 1) {
        float t = __shfl_up(inc, off);
        if (lane >= off) inc += t;
    }
    float ex = __shfl_up(inc, 1);
    if (lane == 0) ex = 0.0f;
    *(float4*)(sc_ws + sb) = make_float4(ex, ex + l1, ex + l2, ex + l3);
    if (lane == 63) tot_ws[bd] = inc;

    #pragma unroll 1
    for (int n = 0; n < NS; n++) {
        const size_t base = ((size_t)bd*NS + n)*NCB + lane*4;
        float4 av = *(const float4*)(ap_ws + base);
        float4 rv = *(const float4*)(rs_ws + base);
        float Ac = av.x, Bc = rv.x;
        Bc = fmaf(av.y, Bc, rv.y); Ac *= av.y;
        Bc = fmaf(av.z, Bc, rv.z); Ac *= av.z;
        Bc = fmaf(av.w, Bc, rv.w); Ac *= av.w;
        #pragma unroll
        for (int off = 1; off < 64; off <<= 1) {
            float aP = __shfl_up(Ac, off);
            float bP = __shfl_up(Bc, off);
            if (lane >= off) { Bc = fmaf(Ac, bP, Bc); Ac *= aP; }
        }
        float pB = __shfl_up(Bc, 1);
        if (lane == 0) pB = 0.0f;
        float r  = pB;
        float o0 = r; r = fmaf(av.x, r, rv.x);
        float o1 = r; r = fmaf(av.y, r, rv.y);
        float o2 = r; r = fmaf(av.z, r, rv.z);
        float o3 = r;
        *(float4*)(rs_ws + base) = make_float4(o0, o1, o2, o3);
    }
}

// =============== kD: damp-gated final scan + y ===============
__global__ __launch_bounds__(320) void kD(
    const h16* __restrict__ dh, const h16* __restrict__ uh,
    const h16* __restrict__ Bh, const h16* __restrict__ Ch,
    const float* __restrict__ A_log, const float* __restrict__ D_param,
    const float* __restrict__ rs_ws, const float* __restrict__ sc_ws,
    const float* __restrict__ tot_ws, float* __restrict__ out)
{
    __shared__ float ylT[20*132];
    const int tid = threadIdx.x;
    const int d   = tid >> 4;
    const int s   = tid & 15;
    const int c   = blockIdx.x;
    const int b   = blockIdx.y;
    const int bd  = b*DI + d;
    const size_t t0 = (size_t)c*TBLK + s*8;

    const float Tot = tot_ws[bd];
    float A_dn[NS];
    float Amax = -1e30f;
    #pragma unroll
    for (int n = 0; n < NS; n++) {
        A_dn[n] = -__expf(A_log[d*NS + n]);
        Amax = fmaxf(Amax, A_dn[n]);
    }
    const float pref_end = (c + 1 < NCB) ? sc_ws[(size_t)bd*NCB + c + 1] : Tot;
    const bool active = fmaf(Amax, Tot - pref_end, 40.0f) > 0.0f;

    float u8[8];
    { half8 hv = *(const half8*)(uh + (size_t)bd*L_ + t0);
      #pragma unroll
      for (int j = 0; j < 8; j++) u8[j] = (float)hv[j]; }
    const float Dd = D_param[d];
    float yv[8];
    #pragma unroll
    for (int j = 0; j < 8; j++) yv[j] = u8[j]*Dd;

    if (active) {
        float d8[8], du8[8];
        { half8 hv = *(const half8*)(dh + (size_t)bd*L_ + t0);
          #pragma unroll
          for (int j = 0; j < 8; j++) d8[j] = (float)hv[j]; }
        #pragma unroll
        for (int j = 0; j < 8; j++) du8[j] = d8[j]*u8[j];

        float lp[8];
        { float run = 0.0f;
          #pragma unroll
          for (int j = 0; j < 8; j++) { run += d8[j]; lp[j] = run; } }
        float inc = lp[7];
        SUMSCAN16(inc);
        float ex = dppf<ROW_SHR1>(0.0f, inc);
        const float basep = sc_ws[(size_t)bd*NCB + c] + ex;

        float rin[NS];
        #pragma unroll
        for (int n = 0; n < NS; n++) rin[n] = rs_ws[((size_t)bd*NS + n)*NCB + c];

        float yacc[8];
        #pragma unroll
        for (int j = 0; j < 8; j++) yacc[j] = 0.0f;

        half8 bv0 = *(const half8*)(Bh + (size_t)(b*NS + 0)*L_ + t0);
        half8 cv0 = *(const half8*)(Ch + (size_t)(b*NS + 0)*L_ + t0);
        half8 bv1 = *(const half8*)(Bh + (size_t)(b*NS + 1)*L_ + t0);
        half8 cv1 = *(const half8*)(Ch + (size_t)(b*NS + 1)*L_ + t0);

        #pragma unroll 1
        for (int n = 0; n < NS; n++) {
            half8 bv = bv0, cv = cv0;
            bv0 = bv1; cv0 = cv1;
            if (n + 2 < NS) {
                bv1 = *(const half8*)(Bh + (size_t)(b*NS + n + 2)*L_ + t0);
                cv1 = *(const half8*)(Ch + (size_t)(b*NS + n + 2)*L_ + t0);
            }
            float a8[8], b8[8];
            #pragma unroll
            for (int j = 0; j < 8; j++) {
                a8[j] = __expf(A_dn[n]*d8[j]);
                b8[j] = du8[j]*(float)bv[j];
            }
            float Ac = 1.0f, Bc = 0.0f;
            #pragma unroll
            for (int j = 0; j < 8; j++) { Bc = fmaf(a8[j], Bc, b8[j]); Ac *= a8[j]; }
            OPSCAN16(Ac, Bc);
            float pA = dppf<ROW_SHR1>(1.0f, Ac);
            float pB = dppf<ROW_SHR1>(0.0f, Bc);
            float r  = fmaf(pA, rin[n], pB);

            float G[8];
            G[7] = __expf(A_dn[n]*(Tot - (basep + lp[7])));
            #pragma unroll
            for (int j = 6; j >= 0; j--) G[j] = G[j+1]*a8[j+1];
            #pragma unroll
            for (int j = 0; j < 8; j++) {
                r = fmaf(a8[j], r, b8[j]);
                float damp = G[j] * __builtin_amdgcn_rcpf(G[j] + 1e-12f);
                yacc[j] = fmaf((float)cv[j]*damp, r, yacc[j]);
            }
        }
        #pragma unroll
        for (int j = 0; j < 8; j++) yv[j] = fmaf(u8[j], Dd, yacc[j]);
    }

    *(float4*)&ylT[d*132 + 8*s]     = *(float4*)(yv);
    *(float4*)&ylT[d*132 + 8*s + 4] = *(float4*)(yv + 4);
    __syncthreads();

    float4* ob4 = (float4*)(out + ((size_t)b*L_ + (size_t)c*TBLK)*DI);
    for (int i = tid; i < TBLK*DI/4; i += 320) {
        int t = i / 5, qq = (i - t*5)*4;
        ob4[i] = make_float4(ylT[qq*132 + t], ylT[(qq+1)*132 + t],
                             ylT[(qq+2)*132 + t], ylT[(qq+3)*132 + t]);
    }
}

extern "C" void kernel_launch(void* const* d_in, const int* in_sizes, int n_in,
                              void* d_out, int out_size, void* d_ws, size_t ws_size,
                              hipStream_t stream) {
    const float* x      = (const float*)d_in[0];
    const float* w_in   = (const float*)d_in[1];
    const float* b_in   = (const float*)d_in[2];
    const float* conv_k = (const float*)d_in[3];
    const float* conv_b = (const float*)d_in[4];
    const float* w_x    = (const float*)d_in[5];
    const float* b_x    = (const float*)d_in[6];
    const float* w_dt   = (const float*)d_in[7];
    const float* b_dt   = (const float*)d_in[8];
    const float* A_log  = (const float*)d_in[9];
    const float* D_par  = (const float*)d_in[10];
    float* out = (float*)d_out;
    float* ws  = (float*)d_ws;

    float* ap_ws  = ws + OFF_AP;
    float* rs_ws  = ws + OFF_RS;
    float* sc_ws  = ws + OFF_SC;
    float* tot_ws = ws + OFF_TOT;
    float* beff   = ws + OFF_BEFF;
    h16*   hbase  = (h16*)(ws + OFF_H16);
    h16* dh  = hbase + HD;
    h16* uh  = hbase + HU;
    h16* Bh  = hbase + HB;
    h16* Ch  = hbase + HC;
    h16* wts = hbase + HW;

    k0<<<1, 320, 0, stream>>>(w_in, b_in, conv_k, conv_b, w_x, w_dt, b_dt, b_x,
                              wts, beff);
    k1<<<dim3(NCB, B_), 320, 0, stream>>>(x, wts, beff, A_log,
                                          dh, uh, Bh, Ch,
                                          ap_ws, rs_ws, sc_ws);
    kC2<<<B_*DI, 64, 0, stream>>>(ap_ws, rs_ws, sc_ws, tot_ws);
    kD<<<dim3(NCB, B_), 320, 0, stream>>>(dh, uh, Bh, Ch, A_log, D_par,
                                          rs_ws, sc_ws, tot_ws, out);
}

// Round 11
// 120.692 us; speedup vs baseline: 1.2190x; 1.0358x over previous
//
#include <hip/hip_runtime.h>
#include <math.h>

#define B_   4
#define L_   32768
#define DI   20
#define NS   10
#define TBLK 128          // timesteps per chunk/block
#define NCB  256          // chunks per batch

// fp32 offsets in ws (floats)
#define OFF_AP   0u
#define OFF_RS   204800u
#define OFF_SC   409600u
#define OFF_TOT  430080u
#define OFF_BEFF 430160u   // 20 floats
#define OFF_H16  430192u   // h16 region (16B aligned)
// half offsets within h16 region
#define HD  0u             // delta [80][32768]
#define HU  2621440u       // u
#define HB  5242880u       // B [40][32768]
#define HC  6553600u       // C
#define HW  7864320u       // preformatted weights (2585 halves)
// weight block sub-offsets (halves)
#define WMT 0              // MeffT [20][72], cols 60..71 = 0
#define WWX 1440           // WxT   [25][40], cols 20..39 = 0
#define WWD 2440           // w_dt  100
#define WBD 2540           // b_dt  20
#define WBX 2560           // b_x   25

typedef _Float16 h16;
typedef _Float16 half8 __attribute__((ext_vector_type(8)));
typedef _Float16 half4 __attribute__((ext_vector_type(4)));
typedef float f32x4 __attribute__((ext_vector_type(4)));

// ---- DPP helpers: row_shr within 16-lane rows, OOB lanes -> identity ----
template<int CTRL>
__device__ __forceinline__ float dppf(float idv, float src) {
    union U { float f; int i; };
    U o, s, r; o.f = idv; s.f = src;
    r.i = __builtin_amdgcn_update_dpp(o.i, s.i, CTRL, 0xf, 0xf, false);
    return r.f;
}
#define ROW_SHR1 0x111
#define ROW_SHR2 0x112
#define ROW_SHR4 0x114
#define ROW_SHR8 0x118

#define OPSCAN16(Ac, Bc) \
    { float aP = dppf<ROW_SHR1>(1.0f, Ac); float bP = dppf<ROW_SHR1>(0.0f, Bc); \
      Bc = fmaf(Ac, bP, Bc); Ac *= aP; \
      aP = dppf<ROW_SHR2>(1.0f, Ac); bP = dppf<ROW_SHR2>(0.0f, Bc); \
      Bc = fmaf(Ac, bP, Bc); Ac *= aP; \
      aP = dppf<ROW_SHR4>(1.0f, Ac); bP = dppf<ROW_SHR4>(0.0f, Bc); \
      Bc = fmaf(Ac, bP, Bc); Ac *= aP; \
      aP = dppf<ROW_SHR8>(1.0f, Ac); bP = dppf<ROW_SHR8>(0.0f, Bc); \
      Bc = fmaf(Ac, bP, Bc); Ac *= aP; }

#define SUMSCAN16(v) \
    { v += dppf<ROW_SHR1>(0.0f, v); v += dppf<ROW_SHR2>(0.0f, v); \
      v += dppf<ROW_SHR4>(0.0f, v); v += dppf<ROW_SHR8>(0.0f, v); }

// ---- k1 LDS layout (halves), POOLH = 7956 (15912 B) ----
#define XS_   0
#define MT_   2640
#define UL_   0
#define DS__  0
#define DUS_  2720
#define XP5_  4608
#define BS_   5448
#define WXo   6808
#define WDTo  7808
#define BDTo  7908
#define BXo   7928
#define POOLH 7956

// =============== k0: one-block weight preformatting ===============
__global__ __launch_bounds__(320) void k0(
    const float* __restrict__ w_in, const float* __restrict__ b_in,
    const float* __restrict__ conv_k, const float* __restrict__ conv_b,
    const float* __restrict__ w_x, const float* __restrict__ w_dt,
    const float* __restrict__ b_dt, const float* __restrict__ b_x,
    h16* __restrict__ wts, float* __restrict__ beff)
{
    __shared__ float W[1600];   // w_in 20x20 @0, conv_k @400
    const int tid = threadIdx.x;
    for (int i = tid; i < 400;  i += 320) W[i]       = w_in[(i/20)*40 + (i%20)];
    for (int i = tid; i < 1200; i += 320) W[400 + i] = conv_k[i];
    __syncthreads();
    for (int e = tid; e < 1200; e += 320) {
        int cc = e/20, o = e - cc*20;
        int w = cc/20, i = cc - w*20;
        float acc = 0.0f;
        #pragma unroll
        for (int op = 0; op < 20; op++)
            acc = fmaf(W[i*20 + op], W[400 + (w*20 + op)*20 + o], acc);
        wts[WMT + o*72 + cc] = (h16)acc;
    }
    for (int i = tid; i < 240; i += 320) {          // zero MT cols 60..71
        int o = i/12, cc = 60 + (i - (i/12)*12);
        wts[WMT + o*72 + cc] = (h16)0.0f;
    }
    for (int i = tid; i < 1000; i += 320) {         // WxT[j][k=d]
        int j = i/40, k = i - j*40;
        wts[WWX + i] = (k < 20) ? (h16)w_x[k*25 + j] : (h16)0.0f;
    }
    for (int i = tid; i < 100; i += 320) wts[WWD + i] = (h16)w_dt[i];
    if (tid < 20) wts[WBD + tid] = (h16)b_dt[tid];
    if (tid < 25) wts[WBX + tid] = (h16)b_x[tid];
    if (tid < 20) {
        float be = conv_b[tid];
        #pragma unroll
        for (int w = 0; w < 3; w++)
            #pragma unroll
            for (int op = 0; op < 20; op++)
                be = fmaf(b_in[op], W[400 + (w*20 + op)*20 + tid], be);
        beff[tid] = be;
    }
}

// =============== k1: MFMA front-end + chunk-local scan ===============
__global__ __launch_bounds__(320) void k1(
    const float* __restrict__ x, const h16* __restrict__ wts,
    const float* __restrict__ beff, const float* __restrict__ A_log,
    h16* __restrict__ dh, h16* __restrict__ uh,
    h16* __restrict__ Bh, h16* __restrict__ Ch,
    float* __restrict__ ap_ws, float* __restrict__ rs_ws, float* __restrict__ sc_ws)
{
    __shared__ __align__(16) h16 P[POOLH];
    __shared__ float beff_s[20];

    const int tid = threadIdx.x;
    const int c   = blockIdx.x;
    const int b   = blockIdx.y;
    const int l0  = c * TBLK;

    // ---------- P0: copy preformatted weights + flat x window ----------
    {
        const int* src = (const int*)(wts + WMT);     // 1440 halves = 720 ints
        int* dst = (int*)&P[MT_];
        for (int i = tid; i < 720; i += 320) dst[i] = src[i];
        const int* s2 = (const int*)(wts + WWX);      // 1145 halves
        int* d2 = (int*)&P[WXo];
        for (int i = tid; i < 572; i += 320) d2[i] = s2[i];
        if (tid == 0) P[WXo + 1144] = wts[WWX + 1144];
        if (tid < 20) beff_s[tid] = beff[tid];
    }
    {
        const float* xb = x + ((size_t)b*L_ + l0)*DI - 2*DI;
        for (int i = tid; i < 1320; i += 320) {
            float2 v;
            if (i >= 1300 || (c == 0 && i < 20)) v = make_float2(0.0f, 0.0f);
            else v = *(const float2*)(xb + 2*i);
            P[XS_ + 2*i]     = (h16)v.x;
            P[XS_ + 2*i + 1] = (h16)v.y;
        }
    }
    __syncthreads();

    // ---------- P2: u_pre = Xflat @ Meff (MFMA), +beff, silu ----------
    const int wv  = tid >> 6;
    const int ln  = tid & 63;
    const int m16 = ln & 15;
    const int q   = ln >> 4;
    float uval[4][4];
    if (wv < 4) {
        #pragma unroll
        for (int jj = 0; jj < 4; jj++) {
            int job = wv*4 + jj, mt = job >> 1, nt = job & 1;
            int t_row = mt*16 + m16;
            int dcol  = nt*16 + m16;
            int dmin  = dcol < 20 ? dcol : 19;
            f32x4 acc = {0.0f, 0.0f, 0.0f, 0.0f};
            #pragma unroll
            for (int kh = 0; kh < 2; kh++) {
                half8 af, bf;
                int ab = XS_ + t_row*20 + kh*32 + (q<<3);
                *(half4*)&af         = *(const half4*)&P[ab];
                *(((half4*)&af) + 1) = *(const half4*)&P[ab + 4];
                int bb = MT_ + dmin*72 + kh*32 + (q<<3);
                *(half4*)&bf         = *(const half4*)&P[bb];
                *(((half4*)&bf) + 1) = *(const half4*)&P[bb + 4];
                acc = __builtin_amdgcn_mfma_f32_16x16x32_f16(af, bf, acc, 0, 0, 0);
            }
            float bfv = beff_s[dmin];
            #pragma unroll
            for (int r = 0; r < 4; r++) {
                float a = acc[r] + bfv;
                uval[jj][r] = a * __builtin_amdgcn_rcpf(1.0f + __expf(-a));
            }
        }
    }
    __syncthreads();   // b2: XS/MT dead -> UL may overwrite

    if (wv < 4) {
        #pragma unroll
        for (int jj = 0; jj < 4; jj++) {
            int job = wv*4 + jj, mt = job >> 1, nt = job & 1;
            int dcol = nt*16 + m16;
            if (dcol < 20) {
                #pragma unroll
                for (int r = 0; r < 4; r++)
                    P[UL_ + (mt*16 + q*4 + r)*36 + dcol] = (h16)uval[jj][r];
            }
        }
    }
    // NOTE: UL cols 20..31 stay stale (finite) — WxT rows k>=20 are zero,
    // so the P3 MFMA contribution of those k is exactly 0.
    __syncthreads();   // b3

    // ---------- P3: xp = u @ w_x (MFMA), +b_x; stash XP5/BS; Ch direct ----------
    float xv[4][4];
    if (wv < 4) {
        #pragma unroll
        for (int jj = 0; jj < 4; jj++) {
            int job = wv*4 + jj, mt = job >> 1, nt = job & 1;
            int t_row = mt*16 + m16;
            int j     = nt*16 + m16;
            int jmin  = j < 25 ? j : 24;
            f32x4 acc = {0.0f, 0.0f, 0.0f, 0.0f};
            half8 af, bf;
            int ab = UL_ + t_row*36 + (q<<3);
            *(half4*)&af         = *(const half4*)&P[ab];
            *(((half4*)&af) + 1) = *(const half4*)&P[ab + 4];
            int bb = WXo + jmin*40 + (q<<3);
            *(half4*)&bf         = *(const half4*)&P[bb];
            *(((half4*)&bf) + 1) = *(const half4*)&P[bb + 4];
            acc = __builtin_amdgcn_mfma_f32_16x16x32_f16(af, bf, acc, 0, 0, 0);
            float bx = (j < 25) ? (float)P[BXo + j] : 0.0f;
            #pragma unroll
            for (int r = 0; r < 4; r++) xv[jj][r] = acc[r] + bx;
        }
        #pragma unroll
        for (int jj = 0; jj < 4; jj++) {
            int job = wv*4 + jj, mt = job >> 1, nt = job & 1;
            int j = nt*16 + m16;
            #pragma unroll
            for (int r = 0; r < 4; r++) {
                int t = mt*16 + q*4 + r;
                h16 hv = (h16)xv[jj][r];
                if (j < 5)       P[XP5_ + t*5 + j] = hv;
                else if (j < 15) P[BS_ + (j - 5)*136 + t] = hv;
                else if (j < 25) Ch[(size_t)(b*NS + (j - 15))*L_ + l0 + t] = hv;
            }
        }
    }
    __syncthreads();   // b4

    // ---------- P4b: t-threads: uh+Bh coalesced, softmax (u row kept in regs) ----
    h16 urow[20];
    float dl[20];
    if (tid < 128) {
        const int t = tid;
        *(half4*)&urow[0]  = *(const half4*)&P[UL_ + t*36 + 0];
        *(half4*)&urow[4]  = *(const half4*)&P[UL_ + t*36 + 4];
        *(half4*)&urow[8]  = *(const half4*)&P[UL_ + t*36 + 8];
        *(half4*)&urow[12] = *(const half4*)&P[UL_ + t*36 + 12];
        *(half4*)&urow[16] = *(const half4*)&P[UL_ + t*36 + 16];
        #pragma unroll
        for (int d2 = 0; d2 < 20; d2++)
            uh[(size_t)(b*DI + d2)*L_ + l0 + t] = urow[d2];
        #pragma unroll
        for (int n = 0; n < NS; n++)
            Bh[(size_t)(b*NS + n)*L_ + l0 + t] = P[BS_ + n*136 + t];
        float xq[5];
        #pragma unroll
        for (int r = 0; r < 5; r++) xq[r] = (float)P[XP5_ + t*5 + r];
        #pragma unroll
        for (int d2 = 0; d2 < 20; d2++) dl[d2] = (float)P[BDTo + d2];
        #pragma unroll
        for (int r = 0; r < 5; r++) {
            float dv = xq[r];
            #pragma unroll
            for (int d2 = 0; d2 < 20; d2++)
                dl[d2] = fmaf(dv, (float)P[WDTo + r*20 + d2], dl[d2]);
        }
        float mx = dl[0];
        #pragma unroll
        for (int d2 = 1; d2 < 20; d2++) mx = fmaxf(mx, dl[d2]);
        float sm = 0.0f;
        #pragma unroll
        for (int d2 = 0; d2 < 20; d2++) { dl[d2] = __expf(dl[d2] - mx); sm += dl[d2]; }
        float inv = __builtin_amdgcn_rcpf(sm);
        #pragma unroll
        for (int d2 = 0; d2 < 20; d2++) dl[d2] *= inv;
    }
    __syncthreads();   // b5: UL/XP5 dead

    // ---------- P4c: DS/DUS staging + dh ----------
    if (tid < 128) {
        const int t = tid;
        #pragma unroll
        for (int d2 = 0; d2 < 20; d2++) {
            h16 dlh = (h16)dl[d2];
            P[DS__ + d2*136 + t] = dlh;
            P[DUS_ + d2*136 + t] = (h16)((float)dlh * (float)urow[d2]);
            dh[(size_t)(b*DI + d2)*L_ + l0 + t] = dlh;
        }
    }
    __syncthreads();   // b6

    // ---------- P5: chunk-local scan, ILP-restructured ----------
    // Pass 1: all 10 lane-local composes (independent; BS loads batched).
    // Pass 2: 10 interleaved DPP wave-scans (independent 4-stage chains).
    const int d  = tid >> 4;
    const int s  = tid & 15;
    const int bd = b*DI + d;

    float d8[8], du8[8];
    { half8 hv = *(const half8*)&P[DS__ + d*136 + 8*s];
      #pragma unroll
      for (int j = 0; j < 8; j++) d8[j] = (float)hv[j]; }
    { half8 hv = *(const half8*)&P[DUS_ + d*136 + 8*s];
      #pragma unroll
      for (int j = 0; j < 8; j++) du8[j] = (float)hv[j]; }

    float ssum = 0.0f;
    #pragma unroll
    for (int j = 0; j < 8; j++) ssum += d8[j];
    SUMSCAN16(ssum);
    if (s == 15) sc_ws[(size_t)bd*NCB + c] = ssum;

    float A_dn[NS];
    #pragma unroll
    for (int n = 0; n < NS; n++) A_dn[n] = -__expf(A_log[d*NS + n]);

    float AcA[NS], BcA[NS];
    #pragma unroll
    for (int n = 0; n < NS; n++) {
        half8 bv = *(const half8*)&P[BS_ + n*136 + 8*s];
        float Ac = 1.0f, Bc = 0.0f;
        #pragma unroll
        for (int j = 0; j < 8; j++) {
            float a = __expf(A_dn[n]*d8[j]);
            Bc = fmaf(a, Bc, du8[j]*(float)bv[j]);
            Ac *= a;
        }
        AcA[n] = Ac; BcA[n] = Bc;
    }
    #pragma unroll
    for (int n = 0; n < NS; n++) { OPSCAN16(AcA[n], BcA[n]); }
    if (s == 15) {
        const size_t o0 = ((size_t)bd*NS)*NCB + c;
        #pragma unroll
        for (int n = 0; n < NS; n++) {
            ap_ws[o0 + (size_t)n*NCB] = AcA[n];
            rs_ws[o0 + (size_t)n*NCB] = BcA[n];
        }
    }
}

// =============== kC2: inter-chunk scan (one wave per (b,d)) ===============
__global__ __launch_bounds__(64) void kC2(
    const float* __restrict__ ap_ws, float* __restrict__ rs_ws,
    float* __restrict__ sc_ws, float* __restrict__ tot_ws)
{
    const int bd   = blockIdx.x;
    const int lane = threadIdx.x;
    const size_t sb = (size_t)bd*NCB + lane*4;

    float4 sv = *(const float4*)(sc_ws + sb);
    float l1 = sv.x, l2 = l1 + sv.y, l3 = l2 + sv.z, l4 = l3 + sv.w;
    float inc = l4;
    #pragma unroll
    for (int off = 1; off < 64; off <<= 1) {
        float t = __shfl_up(inc, off);
        if (lane >= off) inc += t;
    }
    float ex = __shfl_up(inc, 1);
    if (lane == 0) ex = 0.0f;
    *(float4*)(sc_ws + sb) = make_float4(ex, ex + l1, ex + l2, ex + l3);
    if (lane == 63) tot_ws[bd] = inc;

    #pragma unroll 2
    for (int n = 0; n < NS; n++) {
        const size_t base = ((size_t)bd*NS + n)*NCB + lane*4;
        float4 av = *(const float4*)(ap_ws + base);
        float4 rv = *(const float4*)(rs_ws + base);
        float Ac = av.x, Bc = rv.x;
        Bc = fmaf(av.y, Bc, rv.y); Ac *= av.y;
        Bc = fmaf(av.z, Bc, rv.z); Ac *= av.z;
        Bc = fmaf(av.w, Bc, rv.w); Ac *= av.w;
        #pragma unroll
        for (int off = 1; off < 64; off <<= 1) {
            float aP = __shfl_up(Ac, off);
            float bP = __shfl_up(Bc, off);
            if (lane >= off) { Bc = fmaf(Ac, bP, Bc); Ac *= aP; }
        }
        float pB = __shfl_up(Bc, 1);
        if (lane == 0) pB = 0.0f;
        float r  = pB;
        float o0 = r; r = fmaf(av.x, r, rv.x);
        float o1 = r; r = fmaf(av.y, r, rv.y);
        float o2 = r; r = fmaf(av.z, r, rv.z);
        float o3 = r;
        *(float4*)(rs_ws + base) = make_float4(o0, o1, o2, o3);
    }
}

// =============== kD: damp-gated final scan + y ===============
__global__ __launch_bounds__(320) void kD(
    const h16* __restrict__ dh, const h16* __restrict__ uh,
    const h16* __restrict__ Bh, const h16* __restrict__ Ch,
    const float* __restrict__ A_log, const float* __restrict__ D_param,
    const float* __restrict__ rs_ws, const float* __restrict__ sc_ws,
    const float* __restrict__ tot_ws, float* __restrict__ out)
{
    __shared__ float ylT[20*132];
    const int tid = threadIdx.x;
    const int d   = tid >> 4;
    const int s   = tid & 15;
    const int c   = blockIdx.x;
    const int b   = blockIdx.y;
    const int bd  = b*DI + d;
    const size_t t0 = (size_t)c*TBLK + s*8;

    const float Tot = tot_ws[bd];
    float A_dn[NS];
    float Amax = -1e30f;
    #pragma unroll
    for (int n = 0; n < NS; n++) {
        A_dn[n] = -__expf(A_log[d*NS + n]);
        Amax = fmaxf(Amax, A_dn[n]);
    }
    const float pref_end = (c + 1 < NCB) ? sc_ws[(size_t)bd*NCB + c + 1] : Tot;
    const bool active = fmaf(Amax, Tot - pref_end, 40.0f) > 0.0f;

    float u8[8];
    { half8 hv = *(const half8*)(uh + (size_t)bd*L_ + t0);
      #pragma unroll
      for (int j = 0; j < 8; j++) u8[j] = (float)hv[j]; }
    const float Dd = D_param[d];
    float yv[8];
    #pragma unroll
    for (int j = 0; j < 8; j++) yv[j] = u8[j]*Dd;

    if (active) {
        float d8[8], du8[8];
        { half8 hv = *(const half8*)(dh + (size_t)bd*L_ + t0);
          #pragma unroll
          for (int j = 0; j < 8; j++) d8[j] = (float)hv[j]; }
        #pragma unroll
        for (int j = 0; j < 8; j++) du8[j] = d8[j]*u8[j];

        float lp[8];
        { float run = 0.0f;
          #pragma unroll
          for (int j = 0; j < 8; j++) { run += d8[j]; lp[j] = run; } }
        float inc = lp[7];
        SUMSCAN16(inc);
        float ex = dppf<ROW_SHR1>(0.0f, inc);
        const float basep = sc_ws[(size_t)bd*NCB + c] + ex;

        float rin[NS];
        #pragma unroll
        for (int n = 0; n < NS; n++) rin[n] = rs_ws[((size_t)bd*NS + n)*NCB + c];

        float yacc[8];
        #pragma unroll
        for (int j = 0; j < 8; j++) yacc[j] = 0.0f;

        #pragma unroll 2
        for (int n = 0; n < NS; n++) {
            half8 bv = *(const half8*)(Bh + (size_t)(b*NS + n)*L_ + t0);
            half8 cv = *(const half8*)(Ch + (size_t)(b*NS + n)*L_ + t0);
            float a8[8], b8[8];
            #pragma unroll
            for (int j = 0; j < 8; j++) {
                a8[j] = __expf(A_dn[n]*d8[j]);
                b8[j] = du8[j]*(float)bv[j];
            }
            float Ac = 1.0f, Bc = 0.0f;
            #pragma unroll
            for (int j = 0; j < 8; j++) { Bc = fmaf(a8[j], Bc, b8[j]); Ac *= a8[j]; }
            OPSCAN16(Ac, Bc);
            float pA = dppf<ROW_SHR1>(1.0f, Ac);
            float pB = dppf<ROW_SHR1>(0.0f, Bc);
            float r  = fmaf(pA, rin[n], pB);

            float G[8];
            G[7] = __expf(A_dn[n]*(Tot - (basep + lp[7])));
            #pragma unroll
            for (int j = 6; j >= 0; j--) G[j] = G[j+1]*a8[j+1];
            #pragma unroll
            for (int j = 0; j < 8; j++) {
                r = fmaf(a8[j], r, b8[j]);
                float damp = G[j] * __builtin_amdgcn_rcpf(G[j] + 1e-12f);
                yacc[j] = fmaf((float)cv[j]*damp, r, yacc[j]);
            }
        }
        #pragma unroll
        for (int j = 0; j < 8; j++) yv[j] = fmaf(u8[j], Dd, yacc[j]);
    }

    *(float4*)&ylT[d*132 + 8*s]     = *(float4*)(yv);
    *(float4*)&ylT[d*132 + 8*s + 4] = *(float4*)(yv + 4);
    __syncthreads();

    float4* ob4 = (float4*)(out + ((size_t)b*L_ + (size_t)c*TBLK)*DI);
    for (int i = tid; i < TBLK*DI/4; i += 320) {
        int t = i / 5, qq = (i - t*5)*4;
        ob4[i] = make_float4(ylT[qq*132 + t], ylT[(qq+1)*132 + t],
                             ylT[(qq+2)*132 + t], ylT[(qq+3)*132 + t]);
    }
}

extern "C" void kernel_launch(void* const* d_in, const int* in_sizes, int n_in,
                              void* d_out, int out_size, void* d_ws, size_t ws_size,
                              hipStream_t stream) {
    const float* x      = (const float*)d_in[0];
    const float* w_in   = (const float*)d_in[1];
    const float* b_in   = (const float*)d_in[2];
    const float* conv_k = (const float*)d_in[3];
    const float* conv_b = (const float*)d_in[4];
    const float* w_x    = (const float*)d_in[5];
    const float* b_x    = (const float*)d_in[6];
    const float* w_dt   = (const float*)d_in[7];
    const float* b_dt   = (const float*)d_in[8];
    const float* A_log  = (const float*)d_in[9];
    const float* D_par  = (const float*)d_in[10];
    float* out = (float*)d_out;
    float* ws  = (float*)d_ws;

    float* ap_ws  = ws + OFF_AP;
    float* rs_ws  = ws + OFF_RS;
    float* sc_ws  = ws + OFF_SC;
    float* tot_ws = ws + OFF_TOT;
    float* beff   = ws + OFF_BEFF;
    h16*   hbase  = (h16*)(ws + OFF_H16);
    h16* dh  = hbase + HD;
    h16* uh  = hbase + HU;
    h16* Bh  = hbase + HB;
    h16* Ch  = hbase + HC;
    h16* wts = hbase + HW;

    k0<<<1, 320, 0, stream>>>(w_in, b_in, conv_k, conv_b, w_x, w_dt, b_dt, b_x,
                              wts, beff);
    k1<<<dim3(NCB, B_), 320, 0, stream>>>(x, wts, beff, A_log,
                                          dh, uh, Bh, Ch,
                                          ap_ws, rs_ws, sc_ws);
    kC2<<<B_*DI, 64, 0, stream>>>(ap_ws, rs_ws, sc_ws, tot_ws);
    kD<<<dim3(NCB, B_), 320, 0, stream>>>(dh, uh, Bh, Ch, A_log, D_par,
                                          rs_ws, sc_ws, tot_ws, out);
}